// Round 4
// baseline (523.706 us; speedup 1.0000x reference)
//
#include <hip/hip_runtime.h>

typedef __attribute__((ext_vector_type(8))) short short8;
typedef __attribute__((ext_vector_type(4))) float f32x4;

constexpr int L = 1024, C = 256, F = 256;
constexpr int NIMG = 256;          // B*M
constexpr int LOUT = 1022;         // L - K + 1
constexpr long MAXROW = (long)NIMG * L - 1;

__device__ inline unsigned short f2bf(float f) {
  union { float f; unsigned u; } v; v.f = f;
  return (unsigned short)((v.u + 0x7FFFu + ((v.u >> 16) & 1u)) >> 16);  // RNE
}

__device__ inline void g2l16(const unsigned short* g, unsigned short* l) {
  __builtin_amdgcn_global_load_lds(
      (const __attribute__((address_space(1))) unsigned int*)g,
      (__attribute__((address_space(3))) unsigned int*)l, 16, 0, 0);
}

// Pre-pass: W (3,256,256) fp32 -> Wt bf16, layout [tile(slab*3+k)][f(256)][kp(32)]
__global__ void wprep(const float* __restrict__ W, unsigned short* __restrict__ Wt) {
  int tid = blockIdx.x * 256 + threadIdx.x;       // exactly 768*256 threads
  int kc = tid >> 8, f = tid & 255;               // coalesced read of W[tid]
  int k = kc >> 8, c = kc & 255;
  int slab = c >> 5, kp = c & 31;
  Wt[(size_t)(((slab * 3 + k) * 256 + f) * 32 + kp)] = f2bf(W[tid]);
}

// R2 geometry (512 thr, 128Lx256F block, 64x64 wave tile, 2 blocks/CU) with the
// m201-style 4-phase interleave per k-step: phase = {quadrant ds_reads | stage
// -> barrier -> lgkm0 -> setprio MFMA x4 -> barrier}. Counted vmcnt at step end
// only (drain B(t+1); av = 2 loads/wave, w0 +2 tail -> slightly stricter).
__global__ __launch_bounds__(512, 2) void conv_mfma(
    const float* __restrict__ x, const unsigned short* __restrict__ Wt,
    const float* __restrict__ bias, float* __restrict__ y)
{
  __shared__ __align__(16) unsigned short As[2][520 * 8];   // 2 x 8320 B (130 rows x 32 bf16)
  __shared__ __align__(16) unsigned short Bs[3][512 * 16];  // 3 x 16384 B (256 f x 32 bf16)

  const int bid = blockIdx.x;       // 2048 blocks
  const int mt  = bid & 7;          // 8 m-tiles of 128 rows over Lout=1022
  const int img = bid >> 3;         // 256 images
  const int l0  = mt * 128;

  const int tid  = threadIdx.x;
  const int lane = tid & 63;
  const int wv   = tid >> 6;        // 8 waves: 2(M) x 4(F); wave tile 64 x 64
  const int wr   = wv >> 2;
  const int wc   = wv & 3;
  const int lr   = lane & 15;
  const int quad = lane >> 4;

  f32x4 acc[4][4] = {};
  float4 av[2];                     // A chunk tid (2 dwordx4 loads/wave)
  float4 avt[2];                    // tail chunks 512..519 (wave 0 only, +2 loads)

  const long gb = (long)img * L + l0;

  auto issue_A = [&](int slab) {    // global -> regs, rows 0..129 of slab (fp32)
    const int cb = slab * 32;
    long g0 = gb + (tid >> 2); if (g0 > MAXROW) g0 = MAXROW;   // clamped rows feed
    const float* p0 = x + g0 * C + cb + (tid & 3) * 8;         // only masked outputs
    av[0] = *(const float4*)p0; av[1] = *(const float4*)(p0 + 4);
    if (tid < 8) {
      long g2 = gb + 128 + (tid >> 2); if (g2 > MAXROW) g2 = MAXROW;
      const float* p2 = x + g2 * C + cb + (tid & 3) * 8;
      avt[0] = *(const float4*)p2; avt[1] = *(const float4*)(p2 + 4);
    }
  };

  auto pack8 = [&](float4 a, float4 b) {
    short8 r;
    r[0] = (short)f2bf(a.x); r[1] = (short)f2bf(a.y);
    r[2] = (short)f2bf(a.z); r[3] = (short)f2bf(a.w);
    r[4] = (short)f2bf(b.x); r[5] = (short)f2bf(b.y);
    r[6] = (short)f2bf(b.z); r[7] = (short)f2bf(b.w);
    return r;
  };

  auto write_A = [&](int ab2) {     // 520 chunks of 16 B, contiguous -> balanced
    *(short8*)(As[ab2] + (size_t)tid * 8) = pack8(av[0], av[1]);
    if (tid < 8)
      *(short8*)(As[ab2] + (size_t)(512 + tid) * 8) = pack8(avt[0], avt[1]);
  };

  auto stage_B = [&](int tile, int bb) {  // 16 KB contiguous, 2 g2l16/thread
    const unsigned short* bsrc = Wt + (size_t)tile * 8192;
    g2l16(bsrc + (size_t)tid * 8,         Bs[bb] + (size_t)tid * 8);
    g2l16(bsrc + (size_t)(tid + 512) * 8, Bs[bb] + (size_t)(tid + 512) * 8);
  };

#define BAR   __builtin_amdgcn_s_barrier()
#define SBAR  __builtin_amdgcn_sched_barrier(0)
#define LGKM0 asm volatile("s_waitcnt lgkmcnt(0)" ::: "memory")
#define MFMA_QUAD(MP, NP)                                                     \
  do {                                                                        \
    __builtin_amdgcn_s_setprio(1);                                            \
    acc[MP*2+0][NP*2+0] = __builtin_amdgcn_mfma_f32_16x16x32_bf16(            \
        af[MP*2+0], bf[NP*2+0], acc[MP*2+0][NP*2+0], 0, 0, 0);                \
    acc[MP*2+0][NP*2+1] = __builtin_amdgcn_mfma_f32_16x16x32_bf16(            \
        af[MP*2+0], bf[NP*2+1], acc[MP*2+0][NP*2+1], 0, 0, 0);                \
    acc[MP*2+1][NP*2+0] = __builtin_amdgcn_mfma_f32_16x16x32_bf16(            \
        af[MP*2+1], bf[NP*2+0], acc[MP*2+1][NP*2+0], 0, 0, 0);                \
    acc[MP*2+1][NP*2+1] = __builtin_amdgcn_mfma_f32_16x16x32_bf16(            \
        af[MP*2+1], bf[NP*2+1], acc[MP*2+1][NP*2+1], 0, 0, 0);                \
    __builtin_amdgcn_s_setprio(0);                                            \
  } while (0)

  auto read_af = [&](int ab2, int k, int mi) {
    return *(const short8*)(As[ab2] + (wr * 64 + mi * 16 + lr + k) * 32 + quad * 8);
  };
  auto read_bf = [&](int k, int ni) {
    return *(const short8*)(Bs[k] + (wc * 64 + ni * 16 + lr) * 32 + quad * 8);
  };

  // ---- prologue: av(slab0), B0, B1 in flight; write_A drains av (compiler wait)
  issue_A(0);
  stage_B(0, 0);
  stage_B(1, 1);
  write_A(0);
  asm volatile("s_waitcnt vmcnt(2) lgkmcnt(0)" ::: "memory");  // B0 done, A visible
  BAR; SBAR;

  for (int slab = 0; slab < 8; ++slab) {
    const int ab = slab & 1;
#pragma unroll
    for (int k = 0; k < 3; ++k) {
      const int t = slab * 3 + k;
      short8 af[4], bf[4];

      // ---- P0: Q00 reads + stage issue
      af[0] = read_af(ab, k, 0); af[1] = read_af(ab, k, 1);
      bf[0] = read_bf(k, 0);     bf[1] = read_bf(k, 1);
      if (t < 22) stage_B(t + 2, (k + 2) % 3);       // dist-2; buf idx compile-time
      if (k == 0 && slab < 7) issue_A(slab + 1);     // 2-step reg cover (2 loads; w0 4)
      BAR; LGKM0; SBAR;
      MFMA_QUAD(0, 0);
      BAR;

      // ---- P1: Q01
      bf[2] = read_bf(k, 2); bf[3] = read_bf(k, 3);
      BAR; LGKM0; SBAR;
      MFMA_QUAD(0, 1);
      BAR;

      // ---- P2: Q10
      af[2] = read_af(ab, k, 2); af[3] = read_af(ab, k, 3);
      BAR; LGKM0; SBAR;
      MFMA_QUAD(1, 0);
      BAR;

      // ---- P3: Q11 + A pack + end-of-step wait (drain B(t+1), staged at t-1)
      if (k == 2 && slab < 7) write_A(ab ^ 1);       // pack8 waits av via compiler
      // FIFO per wave (issue order: stage_B then av each k0):
      //  k0-end: [B(t+1)2, B(t+2)2, av2]        -> drain B(t+1): vmcnt(4)
      //  k1-end: [B(t+1)2, av2, B(t+2)2]        -> drain B(t+1): vmcnt(4) (av kept)
      //  k2-end: write_A drained av -> [B(t+1)2, B(t+2)2] -> vmcnt(2) + lgkm0
      //  slab7:  k0 [B22,B23] -> vmcnt(2); k1 [B23] -> vmcnt(0); k2 none
      //  (wave0 has +2 avt after av; same counts over-drain it slightly - safe)
      if (slab < 7) {
        if (k < 2) asm volatile("s_waitcnt vmcnt(4)" ::: "memory");
        else       asm volatile("s_waitcnt vmcnt(2) lgkmcnt(0)" ::: "memory");
      } else {
        if (k == 0)      asm volatile("s_waitcnt vmcnt(2)" ::: "memory");
        else if (k == 1) asm volatile("s_waitcnt vmcnt(0)" ::: "memory");
      }
      if (t < 23) { BAR; SBAR; }
      MFMA_QUAD(1, 1);
    }
  }

  // Epilogue: C/D layout col=lane&15, row=quad*4+reg (m89/m91-verified)
  float bv[4];
#pragma unroll
  for (int ni = 0; ni < 4; ++ni)
    bv[ni] = bias[wc * 64 + ni * 16 + lr];

#pragma unroll
  for (int mi = 0; mi < 4; ++mi) {
#pragma unroll
    for (int r = 0; r < 4; ++r) {
      const int lrow = l0 + wr * 64 + mi * 16 + quad * 4 + r;
      if (lrow < LOUT) {
        float* yp = y + ((size_t)img * LOUT + lrow) * F + wc * 64 + lr;
#pragma unroll
        for (int ni = 0; ni < 4; ++ni)
          yp[ni * 16] = acc[mi][ni][r] + bv[ni];
      }
    }
  }
#undef BAR
#undef SBAR
#undef LGKM0
#undef MFMA_QUAD
}

extern "C" void kernel_launch(void* const* d_in, const int* in_sizes, int n_in,
                              void* d_out, int out_size, void* d_ws, size_t ws_size,
                              hipStream_t stream) {
  const float* x = (const float*)d_in[0];   // (8,32,1024,256) fp32
  const float* W = (const float*)d_in[1];   // (3,256,256) fp32
  const float* b = (const float*)d_in[2];   // (256,) fp32
  float* y = (float*)d_out;                 // (8,32,1022,256) fp32
  unsigned short* Wt = (unsigned short*)d_ws;  // 3*256*256*2 = 393,216 B

  wprep<<<768, 256, 0, stream>>>(W, Wt);
  conv_mfma<<<NIMG * 8, 512, 0, stream>>>(x, Wt, b, y);
}

// Round 5
// 470.130 us; speedup vs baseline: 1.1140x; 1.1140x over previous
//
#include <hip/hip_runtime.h>

typedef __attribute__((ext_vector_type(8))) short short8;
typedef __attribute__((ext_vector_type(4))) float f32x4;

constexpr int L = 1024, C = 256, F = 256;
constexpr int NIMG = 256;          // B*M
constexpr int LOUT = 1022;         // L - K + 1
constexpr long MAXROW = (long)NIMG * L - 1;

__device__ inline unsigned short f2bf(float f) {
  union { float f; unsigned u; } v; v.f = f;
  return (unsigned short)((v.u + 0x7FFFu + ((v.u >> 16) & 1u)) >> 16);  // RNE
}

__device__ inline void g2l16(const unsigned short* g, unsigned short* l) {
  __builtin_amdgcn_global_load_lds(
      (const __attribute__((address_space(1))) unsigned int*)g,
      (__attribute__((address_space(3))) unsigned int*)l, 16, 0, 0);
}

// Pre-pass: W (3,256,256) fp32 -> Wt bf16, layout [tile(slab*3+k)][f(256)][kp(32)]
__global__ void wprep(const float* __restrict__ W, unsigned short* __restrict__ Wt) {
  int tid = blockIdx.x * 256 + threadIdx.x;       // exactly 768*256 threads
  int kc = tid >> 8, f = tid & 255;               // coalesced read of W[tid]
  int k = kc >> 8, c = kc & 255;
  int slab = c >> 5, kp = c & 31;
  Wt[(size_t)(((slab * 3 + k) * 256 + f) * 32 + kp)] = f2bf(W[tid]);
}

// R2 geometry (512 thr, 128Lx256F block, 64x64 wave tile, 2 blocks/CU) with
// 2 barrier-regions per slab instead of 3 (16 sync points vs 24):
//   R0(s): taps {0,1} -> 32 MFMA, 16 ds_read; stage tile 3s+2 -> Bs[2]; issue av
//   R1(s): tap {2}    -> 16 MFMA,  8 ds_read; stage 3s+3->Bs[0], 3s+4->Bs[1];
//          write_A (after MFMAs; published by next R0-top lgkm0)
// Every staged tile has 1-region cover; av covered R0->R1. Reads are always
// consumed by MFMAs before the wave's next barrier, so DMA overwrite of a
// buffer in the following region cannot race an in-flight read.
// Register budget is the binding constraint: acc = 64 AGPR; VGPR must stay
// <= 64 for 4 waves/SIMD (2 blocks/CU). launch_bounds(512,4) enforces it.
__global__ __launch_bounds__(512, 4) void conv_mfma(
    const float* __restrict__ x, const unsigned short* __restrict__ Wt,
    const float* __restrict__ bias, float* __restrict__ y)
{
  __shared__ __align__(16) unsigned short As[2][520 * 8];   // 2 x 8320 B (130 rows x 32 bf16)
  __shared__ __align__(16) unsigned short Bs[3][512 * 16];  // 3 x 16384 B (256 f x 32 bf16)

  const int bid = blockIdx.x;       // 2048 blocks
  const int mt  = bid & 7;          // 8 m-tiles of 128 rows over Lout=1022
  const int img = bid >> 3;         // 256 images
  const int l0  = mt * 128;

  const int tid  = threadIdx.x;
  const int lane = tid & 63;
  const int wv   = tid >> 6;        // 8 waves: 2(M) x 4(F); wave tile 64 x 64
  const int wr   = wv >> 2;
  const int wc   = wv & 3;
  const int lr   = lane & 15;
  const int quad = lane >> 4;

  f32x4 acc[4][4] = {};
  float4 av[2];                     // A chunk tid (2 dwordx4 loads/wave)
  float4 avt[2];                    // tail chunks 512..519 (wave 0 only, +2 loads)

  const long gb = (long)img * L + l0;

  auto issue_A = [&](int slab) {    // global -> regs, rows 0..129 of slab (fp32)
    const int cb = slab * 32;
    long g0 = gb + (tid >> 2); if (g0 > MAXROW) g0 = MAXROW;   // clamped rows feed
    const float* p0 = x + g0 * C + cb + (tid & 3) * 8;         // only masked outputs
    av[0] = *(const float4*)p0; av[1] = *(const float4*)(p0 + 4);
    if (tid < 8) {
      long g2 = gb + 128 + (tid >> 2); if (g2 > MAXROW) g2 = MAXROW;
      const float* p2 = x + g2 * C + cb + (tid & 3) * 8;
      avt[0] = *(const float4*)p2; avt[1] = *(const float4*)(p2 + 4);
    }
  };

  auto pack8 = [&](float4 a, float4 b) {
    short8 r;
    r[0] = (short)f2bf(a.x); r[1] = (short)f2bf(a.y);
    r[2] = (short)f2bf(a.z); r[3] = (short)f2bf(a.w);
    r[4] = (short)f2bf(b.x); r[5] = (short)f2bf(b.y);
    r[6] = (short)f2bf(b.z); r[7] = (short)f2bf(b.w);
    return r;
  };

  auto write_A = [&](int ab2) {     // 520 chunks of 16 B, contiguous -> balanced
    *(short8*)(As[ab2] + (size_t)tid * 8) = pack8(av[0], av[1]);
    if (tid < 8)
      *(short8*)(As[ab2] + (size_t)(512 + tid) * 8) = pack8(avt[0], avt[1]);
  };

  auto stage_B = [&](int tile, int bb) {  // 16 KB contiguous, 2 g2l16/thread
    const unsigned short* bsrc = Wt + (size_t)tile * 8192;
    g2l16(bsrc + (size_t)tid * 8,         Bs[bb] + (size_t)tid * 8);
    g2l16(bsrc + (size_t)(tid + 512) * 8, Bs[bb] + (size_t)(tid + 512) * 8);
  };

  auto read_af = [&](int ab2, int k, int mi) {
    return *(const short8*)(As[ab2] + (wr * 64 + mi * 16 + lr + k) * 32 + quad * 8);
  };
  auto read_bf = [&](int kbuf, int ni) {
    return *(const short8*)(Bs[kbuf] + (wc * 64 + ni * 16 + lr) * 32 + quad * 8);
  };

#define BAR  __builtin_amdgcn_s_barrier()
#define SBAR __builtin_amdgcn_sched_barrier(0)

  // ---- prologue: B0, B1, av(0) issued; write_A drains av (compiler wait);
  // R0(0)'s top wait (vmcnt0+lgkm0) finishes the drain before the barrier.
  stage_B(0, 0);
  stage_B(1, 1);
  issue_A(0);
  write_A(0);

  for (int s = 0; s < 8; ++s) {
    const int ab = s & 1;

    // ======== R0(s): taps 0,1 ========
    // top: pending = R1(s-1)'s 4 stage loads (or prologue) -> drain all;
    // lgkm0 publishes write_A(ab) from R1(s-1).
    asm volatile("s_waitcnt vmcnt(0) lgkmcnt(0)" ::: "memory");
    BAR; SBAR;

    stage_B(3 * s + 2, 2);          // Bs[2] not read in R0; consumed in R1(s)
    if (s < 7) issue_A(s + 1);      // av after stage (FIFO: R1-top keeps av)

#pragma unroll
    for (int tap = 0; tap < 2; ++tap) {
      short8 af[4], bf[4];
#pragma unroll
      for (int mi = 0; mi < 4; ++mi) af[mi] = read_af(ab, tap, mi);
#pragma unroll
      for (int ni = 0; ni < 4; ++ni) bf[ni] = read_bf(tap, ni);  // tile 3s+tap
      __builtin_amdgcn_s_setprio(1);
#pragma unroll
      for (int mi = 0; mi < 4; ++mi)
#pragma unroll
        for (int ni = 0; ni < 4; ++ni)
          acc[mi][ni] = __builtin_amdgcn_mfma_f32_16x16x32_bf16(
              af[mi], bf[ni], acc[mi][ni], 0, 0, 0);
      __builtin_amdgcn_s_setprio(0);
    }

    // ======== R1(s): tap 2 ========
    // top: pending (s<7) = [tile 3s+2 (2), av (2)] -> vmcnt(2) drains the tile,
    // keeps av in flight (wave0's avt: same count is stricter, safe).
    // s==7: no av -> vmcnt(0).
    if (s < 7) asm volatile("s_waitcnt vmcnt(2)" ::: "memory");
    else       asm volatile("s_waitcnt vmcnt(0)" ::: "memory");
    BAR; SBAR;

    if (s < 7) {                    // Bs[0]/Bs[1] fully consumed in R0(s)
      stage_B(3 * s + 3, 0);
      stage_B(3 * s + 4, 1);
    }

    {
      short8 af[4], bf[4];
#pragma unroll
      for (int mi = 0; mi < 4; ++mi) af[mi] = read_af(ab, 2, mi);
#pragma unroll
      for (int ni = 0; ni < 4; ++ni) bf[ni] = read_bf(2, ni);    // tile 3s+2
      __builtin_amdgcn_s_setprio(1);
#pragma unroll
      for (int mi = 0; mi < 4; ++mi)
#pragma unroll
        for (int ni = 0; ni < 4; ++ni)
          acc[mi][ni] = __builtin_amdgcn_mfma_f32_16x16x32_bf16(
              af[mi], bf[ni], acc[mi][ni], 0, 0, 0);
      __builtin_amdgcn_s_setprio(0);
    }

    if (s < 7) write_A(ab ^ 1);     // after MFMAs: implicit av-wait off the
                                    // critical path; published at next R0-top
  }

  // Epilogue: C/D layout col=lane&15, row=quad*4+reg (m89/m91-verified)
  float bv[4];
#pragma unroll
  for (int ni = 0; ni < 4; ++ni)
    bv[ni] = bias[wc * 64 + ni * 16 + lr];

#pragma unroll
  for (int mi = 0; mi < 4; ++mi) {
#pragma unroll
    for (int r = 0; r < 4; ++r) {
      const int lrow = l0 + wr * 64 + mi * 16 + quad * 4 + r;
      if (lrow < LOUT) {
        float* yp = y + ((size_t)img * LOUT + lrow) * F + wc * 64 + lr;
#pragma unroll
        for (int ni = 0; ni < 4; ++ni)
          yp[ni * 16] = acc[mi][ni][r] + bv[ni];
      }
    }
  }
#undef BAR
#undef SBAR
}

extern "C" void kernel_launch(void* const* d_in, const int* in_sizes, int n_in,
                              void* d_out, int out_size, void* d_ws, size_t ws_size,
                              hipStream_t stream) {
  const float* x = (const float*)d_in[0];   // (8,32,1024,256) fp32
  const float* W = (const float*)d_in[1];   // (3,256,256) fp32
  const float* b = (const float*)d_in[2];   // (256,) fp32
  float* y = (float*)d_out;                 // (8,32,1022,256) fp32
  unsigned short* Wt = (unsigned short*)d_ws;  // 3*256*256*2 = 393,216 B

  wprep<<<768, 256, 0, stream>>>(W, Wt);
  conv_mfma<<<NIMG * 8, 512, 0, stream>>>(x, Wt, b, y);
}